// Round 1
// baseline (1032.244 us; speedup 1.0000x reference)
//
#include <hip/hip_runtime.h>

#define NN 50000
#define NE 800000
#define DD 128

// ---------------- normalization ----------------
__global__ void init_deg_kernel(float* deg, int n) {
    int i = blockIdx.x * 256 + threadIdx.x;
    if (i < n) deg[i] = 1.0f;  // self-loop weight
}

__global__ void deg_edges_kernel(const int* __restrict__ col, const float* __restrict__ ew,
                                 float* deg, int E) {
    int e = blockIdx.x * 256 + threadIdx.x;
    if (e < E) atomicAdd(&deg[col[e]], ew[e]);
}

__global__ void dinv_kernel(float* deg, int n) {
    int i = blockIdx.x * 256 + threadIdx.x;
    if (i < n) {
        float d = deg[i];
        deg[i] = d > 0.f ? 1.0f / sqrtf(d) : 0.f;  // in-place: deg -> dinv
    }
}

__global__ void norm_kernel(const int* __restrict__ row, const int* __restrict__ col,
                            const float* __restrict__ ew, const float* __restrict__ dinv,
                            float* __restrict__ norm, int E) {
    int e = blockIdx.x * 256 + threadIdx.x;
    if (e < E) norm[e] = dinv[row[e]] * ew[e] * dinv[col[e]];
}

// ---------------- dense GEMM: Y[n x 128] = X[n x 128] @ W[128 x 128] ----------------
// 512 persistent blocks, W staged in LDS (64 KB -> 2 blocks/CU).
__global__ __launch_bounds__(256) void gemm128_kernel(const float* __restrict__ X,
                                                      const float* __restrict__ W,
                                                      float* __restrict__ Y, int n) {
    __shared__ float Wl[128 * 128];
    const float4* W4 = (const float4*)W;
    float4* Wl4 = (float4*)Wl;
    for (int i = threadIdx.x; i < 128 * 128 / 4; i += 256) Wl4[i] = W4[i];
    __syncthreads();

    const int j = threadIdx.x & 127;       // output column
    const int group = threadIdx.x >> 7;    // 2 rows per block per iter
    for (int r = blockIdx.x * 2 + group; r < n; r += gridDim.x * 2) {
        const float4* xr = (const float4*)(X + (size_t)r * DD);
        float acc = 0.f;
#pragma unroll
        for (int k4 = 0; k4 < 32; ++k4) {
            float4 xv = xr[k4];
            acc += xv.x * Wl[(k4 * 4 + 0) * 128 + j];
            acc += xv.y * Wl[(k4 * 4 + 1) * 128 + j];
            acc += xv.z * Wl[(k4 * 4 + 2) * 128 + j];
            acc += xv.w * Wl[(k4 * 4 + 3) * 128 + j];
        }
        Y[(size_t)r * DD + j] = acc;
    }
}

// ---------------- aggregation ----------------
// Write-initialize agg with the self-loop term (no memset needed).
__global__ void selfloop_kernel(const float* __restrict__ dinv, const float* __restrict__ xw,
                                float* __restrict__ agg, int n) {
    int idx = blockIdx.x * 256 + threadIdx.x;
    if (idx < n * DD) {
        int i = idx >> 7;
        float dv = dinv[i];
        agg[idx] = dv * dv * xw[idx];
    }
}

// One 128-thread group per edge: coalesced gather + coalesced atomics.
__global__ void edge_agg_kernel(const int* __restrict__ row, const int* __restrict__ col,
                                const float* __restrict__ norm, const float* __restrict__ xw,
                                float* __restrict__ agg, int E) {
    int e = blockIdx.x * 2 + (threadIdx.x >> 7);
    int d = threadIdx.x & 127;
    if (e < E) {
        int r = row[e], c = col[e];
        float nv = norm[e];
        atomicAdd(&agg[(size_t)c * DD + d], nv * xw[(size_t)r * DD + d]);
    }
}

__global__ void bias_relu_kernel(const float* __restrict__ agg, const float* __restrict__ b,
                                 float* __restrict__ h, int n) {
    int idx = blockIdx.x * 256 + threadIdx.x;
    if (idx < n * DD) h[idx] = fmaxf(agg[idx] + b[idx & 127], 0.f);
}

// ---------------- readout ----------------
__global__ void colsum_partial_kernel(const float* __restrict__ h, float* __restrict__ partial,
                                      int n) {
    // grid 512, block 128
    float acc = 0.f;
    for (int r = blockIdx.x; r < n; r += gridDim.x) acc += h[(size_t)r * DD + threadIdx.x];
    partial[blockIdx.x * DD + threadIdx.x] = acc;
}

__global__ void final_kernel(const float* __restrict__ partial, const float* __restrict__ Wm,
                             const float* __restrict__ bm, float* __restrict__ out, int n) {
    __shared__ float g[DD];
    int t = threadIdx.x;  // 128 threads, 1 block
    float acc = 0.f;
    for (int b = 0; b < 512; ++b) acc += partial[b * DD + t];
    g[t] = acc / (float)n;
    __syncthreads();
    if (t < 10) {
        float o = bm[t];
#pragma unroll
        for (int d = 0; d < DD; ++d) o += g[d] * Wm[d * 10 + t];
        out[t] = o;
    }
}

extern "C" void kernel_launch(void* const* d_in, const int* in_sizes, int n_in,
                              void* d_out, int out_size, void* d_ws, size_t ws_size,
                              hipStream_t stream) {
    const float* x  = (const float*)d_in[0];
    const int*   ei = (const int*)d_in[1];
    const float* ew = (const float*)d_in[2];
    const float* W1 = (const float*)d_in[3];
    const float* b1 = (const float*)d_in[4];
    const float* W2 = (const float*)d_in[5];
    const float* b2 = (const float*)d_in[6];
    const float* Wm = (const float*)d_in[7];
    const float* bm = (const float*)d_in[8];
    float* out = (float*)d_out;

    const int n = in_sizes[0] / DD;   // 50000
    const int E = in_sizes[2];        // 800000
    const int* row = ei;              // edge_index[0] (source)
    const int* col = ei + E;          // edge_index[1] (target)

    float* ws = (float*)d_ws;
    float* bufA    = ws;                       // n*128
    float* bufB    = bufA + (size_t)n * DD;    // n*128
    float* deg     = bufB + (size_t)n * DD;    // n  (becomes dinv in place)
    float* norm    = deg + n;                  // E
    float* partial = norm + E;                 // 512*128

    const int nodeBlocks = (n + 255) / 256;
    const int edgeBlocks = (E + 255) / 256;
    const int elemBlocks = (n * DD + 255) / 256;

    // --- shared normalization ---
    init_deg_kernel<<<nodeBlocks, 256, 0, stream>>>(deg, n);
    deg_edges_kernel<<<edgeBlocks, 256, 0, stream>>>(col, ew, deg, E);
    dinv_kernel<<<nodeBlocks, 256, 0, stream>>>(deg, n);
    norm_kernel<<<edgeBlocks, 256, 0, stream>>>(row, col, ew, deg, norm, E);

    // --- layer 1: xw1 -> bufA, agg -> bufB, h1 -> bufA ---
    gemm128_kernel<<<512, 256, 0, stream>>>(x, W1, bufA, n);
    selfloop_kernel<<<elemBlocks, 256, 0, stream>>>(deg, bufA, bufB, n);
    edge_agg_kernel<<<(E + 1) / 2, 256, 0, stream>>>(row, col, norm, bufA, bufB, E);
    bias_relu_kernel<<<elemBlocks, 256, 0, stream>>>(bufB, b1, bufA, n);

    // --- layer 2: xw2 -> bufB, agg -> bufA, h2 -> bufB ---
    gemm128_kernel<<<512, 256, 0, stream>>>(bufA, W2, bufB, n);
    selfloop_kernel<<<elemBlocks, 256, 0, stream>>>(deg, bufB, bufA, n);
    edge_agg_kernel<<<(E + 1) / 2, 256, 0, stream>>>(row, col, norm, bufB, bufA, E);
    bias_relu_kernel<<<elemBlocks, 256, 0, stream>>>(bufA, b2, bufB, n);

    // --- readout ---
    colsum_partial_kernel<<<512, 128, 0, stream>>>(bufB, partial, n);
    final_kernel<<<1, 128, 0, stream>>>(partial, Wm, bm, out, n);
}

// Round 2
// 680.367 us; speedup vs baseline: 1.5172x; 1.5172x over previous
//
#include <hip/hip_runtime.h>

#define DD 128

// ---------------- degree + count ----------------
__global__ void init_kernel(float* deg, int* count, int n) {
    int i = blockIdx.x * 256 + threadIdx.x;
    if (i < n) { deg[i] = 1.0f; count[i] = 0; }  // self-loop weight 1
}

__global__ void deg_count_kernel(const int* __restrict__ col, const float* __restrict__ ew,
                                 float* deg, int* count, int E) {
    int e = blockIdx.x * 256 + threadIdx.x;
    if (e < E) {
        int c = col[e];
        atomicAdd(&deg[c], ew[e]);
        atomicAdd(&count[c], 1);
    }
}

__global__ void dinv_kernel(float* deg, int n) {
    int i = blockIdx.x * 256 + threadIdx.x;
    if (i < n) {
        float d = deg[i];
        deg[i] = d > 0.f ? 1.0f / sqrtf(d) : 0.f;  // in-place: deg -> dinv
    }
}

// ---------------- CSR build ----------------
// Single-block exclusive scan over n counts -> start[0..n], cursor copy.
__global__ void scan_kernel(const int* __restrict__ count, int* __restrict__ start,
                            int* __restrict__ cursor, int n) {
    __shared__ int sums[256];
    int t = threadIdx.x;
    int chunk = (n + 255) / 256;
    int lo = t * chunk, hi = min(lo + chunk, n);
    int s = 0;
    for (int i = lo; i < hi; ++i) s += count[i];
    sums[t] = s;
    __syncthreads();
    if (t == 0) {
        int run = 0;
        for (int i = 0; i < 256; ++i) { int v = sums[i]; sums[i] = run; run += v; }
    }
    __syncthreads();
    int run = sums[t];
    for (int i = lo; i < hi; ++i) {
        start[i] = run; cursor[i] = run; run += count[i];
    }
    if (hi == n) start[n] = run;
}

// Scatter edges into CSR order; fuse norm computation.
__global__ void scatter_kernel(const int* __restrict__ row, const int* __restrict__ col,
                               const float* __restrict__ ew, const float* __restrict__ dinv,
                               int* cursor, int* __restrict__ srow, float* __restrict__ snorm,
                               int E) {
    int e = blockIdx.x * 256 + threadIdx.x;
    if (e < E) {
        int c = col[e], r = row[e];
        int pos = atomicAdd(&cursor[c], 1);
        srow[pos] = r;
        snorm[pos] = dinv[r] * ew[e] * dinv[c];
    }
}

// ---------------- dense GEMM: Y[n x 128] = X[n x 128] @ W[128 x 128] ----------------
__global__ __launch_bounds__(256) void gemm128_kernel(const float* __restrict__ X,
                                                      const float* __restrict__ W,
                                                      float* __restrict__ Y, int n) {
    __shared__ float Wl[128 * 128];
    const float4* W4 = (const float4*)W;
    float4* Wl4 = (float4*)Wl;
    for (int i = threadIdx.x; i < 128 * 128 / 4; i += 256) Wl4[i] = W4[i];
    __syncthreads();

    const int j = threadIdx.x & 127;
    const int group = threadIdx.x >> 7;
    for (int r = blockIdx.x * 2 + group; r < n; r += gridDim.x * 2) {
        const float4* xr = (const float4*)(X + (size_t)r * DD);
        float acc = 0.f;
#pragma unroll
        for (int k4 = 0; k4 < 32; ++k4) {
            float4 xv = xr[k4];
            acc += xv.x * Wl[(k4 * 4 + 0) * 128 + j];
            acc += xv.y * Wl[(k4 * 4 + 1) * 128 + j];
            acc += xv.z * Wl[(k4 * 4 + 2) * 128 + j];
            acc += xv.w * Wl[(k4 * 4 + 3) * 128 + j];
        }
        Y[(size_t)r * DD + j] = acc;
    }
}

// ---------------- pull aggregation: one block per node, no atomics ----------------
// Fuses self-loop init + bias + ReLU.
__global__ __launch_bounds__(128) void agg_kernel(const int* __restrict__ start,
                                                  const int* __restrict__ srow,
                                                  const float* __restrict__ snorm,
                                                  const float* __restrict__ dinv,
                                                  const float* __restrict__ xw,
                                                  const float* __restrict__ bias,
                                                  float* __restrict__ h, int n) {
    int i = blockIdx.x;
    int d = threadIdx.x;
    float dv = dinv[i];
    float acc = dv * dv * xw[(size_t)i * DD + d];
    int s = start[i], e = start[i + 1];
    for (int k = s; k < e; ++k) {
        acc += snorm[k] * xw[(size_t)srow[k] * DD + d];
    }
    h[(size_t)i * DD + d] = fmaxf(acc + bias[d], 0.f);
}

// ---------------- readout ----------------
__global__ void colsum_partial_kernel(const float* __restrict__ h, float* __restrict__ partial,
                                      int n) {
    float acc = 0.f;
    for (int r = blockIdx.x; r < n; r += gridDim.x) acc += h[(size_t)r * DD + threadIdx.x];
    partial[blockIdx.x * DD + threadIdx.x] = acc;
}

__global__ void final_kernel(const float* __restrict__ partial, const float* __restrict__ Wm,
                             const float* __restrict__ bm, float* __restrict__ out, int n) {
    __shared__ float g[DD];
    int t = threadIdx.x;
    float acc = 0.f;
    for (int b = 0; b < 512; ++b) acc += partial[b * DD + t];
    g[t] = acc / (float)n;
    __syncthreads();
    if (t < 10) {
        float o = bm[t];
#pragma unroll
        for (int d = 0; d < DD; ++d) o += g[d] * Wm[d * 10 + t];
        out[t] = o;
    }
}

extern "C" void kernel_launch(void* const* d_in, const int* in_sizes, int n_in,
                              void* d_out, int out_size, void* d_ws, size_t ws_size,
                              hipStream_t stream) {
    const float* x  = (const float*)d_in[0];
    const int*   ei = (const int*)d_in[1];
    const float* ew = (const float*)d_in[2];
    const float* W1 = (const float*)d_in[3];
    const float* b1 = (const float*)d_in[4];
    const float* W2 = (const float*)d_in[5];
    const float* b2 = (const float*)d_in[6];
    const float* Wm = (const float*)d_in[7];
    const float* bm = (const float*)d_in[8];
    float* out = (float*)d_out;

    const int n = in_sizes[0] / DD;   // 50000
    const int E = in_sizes[2];        // 800000
    const int* row = ei;              // edge_index[0] (source)
    const int* col = ei + E;          // edge_index[1] (target)

    float* ws = (float*)d_ws;
    float* bufA    = ws;                          // n*128
    float* bufB    = bufA + (size_t)n * DD;       // n*128
    float* deg     = bufB + (size_t)n * DD;       // n (becomes dinv)
    float* snorm   = deg + n;                     // E
    float* partial = snorm + E;                   // 512*128
    int*   count   = (int*)(partial + 512 * DD);  // n
    int*   startA  = count + n;                   // n+1
    int*   cursor  = startA + (n + 1);            // n
    int*   srow    = cursor + n;                  // E

    const int nodeBlocks = (n + 255) / 256;
    const int edgeBlocks = (E + 255) / 256;

    // --- CSR + normalization (shared by both layers) ---
    init_kernel<<<nodeBlocks, 256, 0, stream>>>(deg, count, n);
    deg_count_kernel<<<edgeBlocks, 256, 0, stream>>>(col, ew, deg, count, E);
    dinv_kernel<<<nodeBlocks, 256, 0, stream>>>(deg, n);
    scan_kernel<<<1, 256, 0, stream>>>(count, startA, cursor, n);
    scatter_kernel<<<edgeBlocks, 256, 0, stream>>>(row, col, ew, deg, cursor, srow, snorm, E);

    // --- layer 1 ---
    gemm128_kernel<<<512, 256, 0, stream>>>(x, W1, bufA, n);
    agg_kernel<<<n, 128, 0, stream>>>(startA, srow, snorm, deg, bufA, b1, bufB, n);

    // --- layer 2 ---
    gemm128_kernel<<<512, 256, 0, stream>>>(bufB, W2, bufA, n);
    agg_kernel<<<n, 128, 0, stream>>>(startA, srow, snorm, deg, bufA, b2, bufB, n);

    // --- readout ---
    colsum_partial_kernel<<<512, 128, 0, stream>>>(bufB, partial, n);
    final_kernel<<<1, 128, 0, stream>>>(partial, Wm, bm, out, n);
}

// Round 3
// 611.822 us; speedup vs baseline: 1.6872x; 1.1120x over previous
//
#include <hip/hip_runtime.h>

#define DD 128

// ---------------- degree + count ----------------
__global__ void init_kernel(float* deg, int* count, int n) {
    int i = blockIdx.x * 256 + threadIdx.x;
    if (i < n) { deg[i] = 1.0f; count[i] = 0; }  // self-loop weight 1
}

__global__ void deg_count_kernel(const int* __restrict__ col, const float* __restrict__ ew,
                                 float* deg, int* count, int E) {
    int e = blockIdx.x * 256 + threadIdx.x;
    if (e < E) {
        int c = col[e];
        atomicAdd(&deg[c], ew[e]);
        atomicAdd(&count[c], 1);
    }
}

__global__ void dinv_kernel(float* deg, int n) {
    int i = blockIdx.x * 256 + threadIdx.x;
    if (i < n) {
        float d = deg[i];
        deg[i] = d > 0.f ? 1.0f / sqrtf(d) : 0.f;  // in-place: deg -> dinv
    }
}

// ---------------- 3-stage parallel scan ----------------
__global__ void scan_partial_kernel(const int* __restrict__ count, int* __restrict__ blockSum,
                                    int n) {
    __shared__ int s[256];
    int i = blockIdx.x * 256 + threadIdx.x;
    s[threadIdx.x] = i < n ? count[i] : 0;
    __syncthreads();
    for (int off = 128; off > 0; off >>= 1) {
        if (threadIdx.x < off) s[threadIdx.x] += s[threadIdx.x + off];
        __syncthreads();
    }
    if (threadIdx.x == 0) blockSum[blockIdx.x] = s[0];
}

__global__ void scan_offsets_kernel(const int* __restrict__ blockSum, int* __restrict__ blockOff,
                                    int nb) {
    __shared__ int s[256];
    int t = threadIdx.x;
    int v = t < nb ? blockSum[t] : 0;
    s[t] = v;
    __syncthreads();
    for (int off = 1; off < 256; off <<= 1) {
        int add = t >= off ? s[t - off] : 0;
        __syncthreads();
        s[t] += add;
        __syncthreads();
    }
    if (t < nb) blockOff[t] = s[t] - v;  // exclusive
}

__global__ void scan_final_kernel(const int* __restrict__ count, const int* __restrict__ blockOff,
                                  int* __restrict__ start, int* __restrict__ cursor, int n) {
    __shared__ int s[256];
    int t = threadIdx.x;
    int i = blockIdx.x * 256 + t;
    int v = i < n ? count[i] : 0;
    s[t] = v;
    __syncthreads();
    for (int off = 1; off < 256; off <<= 1) {
        int add = t >= off ? s[t - off] : 0;
        __syncthreads();
        s[t] += add;
        __syncthreads();
    }
    int excl = s[t] - v + blockOff[blockIdx.x];
    if (i < n) {
        start[i] = excl;
        cursor[i] = excl;
        if (i == n - 1) start[n] = excl + v;
    }
}

// Scatter edges into CSR order; fuse norm computation.
__global__ void scatter_kernel(const int* __restrict__ row, const int* __restrict__ col,
                               const float* __restrict__ ew, const float* __restrict__ dinv,
                               int* cursor, int* __restrict__ srow, float* __restrict__ snorm,
                               int E) {
    int e = blockIdx.x * 256 + threadIdx.x;
    if (e < E) {
        int c = col[e], r = row[e];
        int pos = atomicAdd(&cursor[c], 1);
        srow[pos] = r;
        snorm[pos] = dinv[r] * ew[e] * dinv[c];
    }
}

// ---------------- dense GEMM: Y[n x 128] = X[n x 128] @ W[128 x 128] ----------------
// 4 rows per thread -> 4 independent FMA chains, W-column LDS reads amortized 4x.
__global__ __launch_bounds__(256) void gemm128_kernel(const float* __restrict__ X,
                                                      const float* __restrict__ W,
                                                      float* __restrict__ Y, int n) {
    __shared__ float Wl[128 * 128];
    const float4* W4 = (const float4*)W;
    float4* Wl4 = (float4*)Wl;
    for (int i = threadIdx.x; i < 128 * 128 / 4; i += 256) Wl4[i] = W4[i];
    __syncthreads();

    const int j = threadIdx.x & 127;
    const int g = threadIdx.x >> 7;
    for (int r0 = blockIdx.x * 8 + g * 4; r0 < n; r0 += gridDim.x * 8) {
        if (r0 + 3 < n) {
            const float4* xp = (const float4*)(X + (size_t)r0 * DD);
            float a0 = 0.f, a1 = 0.f, a2 = 0.f, a3 = 0.f;
#pragma unroll 4
            for (int k4 = 0; k4 < 32; ++k4) {
                float4 v0 = xp[k4];
                float4 v1 = xp[32 + k4];
                float4 v2 = xp[64 + k4];
                float4 v3 = xp[96 + k4];
                float w0 = Wl[(4 * k4 + 0) * 128 + j];
                float w1 = Wl[(4 * k4 + 1) * 128 + j];
                float w2 = Wl[(4 * k4 + 2) * 128 + j];
                float w3 = Wl[(4 * k4 + 3) * 128 + j];
                a0 += v0.x * w0 + v0.y * w1 + v0.z * w2 + v0.w * w3;
                a1 += v1.x * w0 + v1.y * w1 + v1.z * w2 + v1.w * w3;
                a2 += v2.x * w0 + v2.y * w1 + v2.z * w2 + v2.w * w3;
                a3 += v3.x * w0 + v3.y * w1 + v3.z * w2 + v3.w * w3;
            }
            Y[(size_t)r0 * DD + j] = a0;
            Y[(size_t)(r0 + 1) * DD + j] = a1;
            Y[(size_t)(r0 + 2) * DD + j] = a2;
            Y[(size_t)(r0 + 3) * DD + j] = a3;
        } else {
            for (int r = r0; r < n; ++r) {
                const float4* xr = (const float4*)(X + (size_t)r * DD);
                float acc = 0.f;
                for (int k4 = 0; k4 < 32; ++k4) {
                    float4 xv = xr[k4];
                    acc += xv.x * Wl[(k4 * 4 + 0) * 128 + j];
                    acc += xv.y * Wl[(k4 * 4 + 1) * 128 + j];
                    acc += xv.z * Wl[(k4 * 4 + 2) * 128 + j];
                    acc += xv.w * Wl[(k4 * 4 + 3) * 128 + j];
                }
                Y[(size_t)r * DD + j] = acc;
            }
        }
    }
}

// ---------------- pull aggregation: one block per node, no atomics ----------------
__global__ __launch_bounds__(128) void agg_kernel(const int* __restrict__ start,
                                                  const int* __restrict__ srow,
                                                  const float* __restrict__ snorm,
                                                  const float* __restrict__ dinv,
                                                  const float* __restrict__ xw,
                                                  const float* __restrict__ bias,
                                                  float* __restrict__ h, int n) {
    int i = blockIdx.x;
    int d = threadIdx.x;
    float dv = dinv[i];
    float acc0 = dv * dv * xw[(size_t)i * DD + d];
    float acc1 = 0.f;
    int s = start[i], e = start[i + 1];
    int k = s;
    for (; k + 1 < e; k += 2) {
        int r0 = srow[k], r1 = srow[k + 1];
        float n0 = snorm[k], n1 = snorm[k + 1];
        acc0 += n0 * xw[(size_t)r0 * DD + d];
        acc1 += n1 * xw[(size_t)r1 * DD + d];
    }
    if (k < e) acc0 += snorm[k] * xw[(size_t)srow[k] * DD + d];
    h[(size_t)i * DD + d] = fmaxf(acc0 + acc1 + bias[d], 0.f);
}

// ---------------- readout ----------------
__global__ void colsum_partial_kernel(const float* __restrict__ h, float* __restrict__ partial,
                                      int n) {
    float acc = 0.f;
    for (int r = blockIdx.x; r < n; r += gridDim.x) acc += h[(size_t)r * DD + threadIdx.x];
    partial[blockIdx.x * DD + threadIdx.x] = acc;
}

__global__ void final_kernel(const float* __restrict__ partial, const float* __restrict__ Wm,
                             const float* __restrict__ bm, float* __restrict__ out, int n) {
    __shared__ float g[DD];
    int t = threadIdx.x;
    float acc = 0.f;
    for (int b = 0; b < 512; ++b) acc += partial[b * DD + t];
    g[t] = acc / (float)n;
    __syncthreads();
    if (t < 10) {
        float o = bm[t];
#pragma unroll
        for (int d = 0; d < DD; ++d) o += g[d] * Wm[d * 10 + t];
        out[t] = o;
    }
}

extern "C" void kernel_launch(void* const* d_in, const int* in_sizes, int n_in,
                              void* d_out, int out_size, void* d_ws, size_t ws_size,
                              hipStream_t stream) {
    const float* x  = (const float*)d_in[0];
    const int*   ei = (const int*)d_in[1];
    const float* ew = (const float*)d_in[2];
    const float* W1 = (const float*)d_in[3];
    const float* b1 = (const float*)d_in[4];
    const float* W2 = (const float*)d_in[5];
    const float* b2 = (const float*)d_in[6];
    const float* Wm = (const float*)d_in[7];
    const float* bm = (const float*)d_in[8];
    float* out = (float*)d_out;

    const int n = in_sizes[0] / DD;   // 50000
    const int E = in_sizes[2];        // 800000
    const int* row = ei;              // edge_index[0] (source)
    const int* col = ei + E;          // edge_index[1] (target)

    const int nodeBlocks = (n + 255) / 256;   // 196
    const int edgeBlocks = (E + 255) / 256;

    float* ws = (float*)d_ws;
    float* bufA    = ws;                          // n*128
    float* bufB    = bufA + (size_t)n * DD;       // n*128
    float* deg     = bufB + (size_t)n * DD;       // n (becomes dinv)
    float* snorm   = deg + n;                     // E
    float* partial = snorm + E;                   // 512*128
    int*   count   = (int*)(partial + 512 * DD);  // n
    int*   startA  = count + n;                   // n+1
    int*   cursor  = startA + (n + 1);            // n
    int*   srow    = cursor + n;                  // E
    int*   blockSum = srow + E;                   // nodeBlocks
    int*   blockOff = blockSum + nodeBlocks;      // nodeBlocks

    // --- CSR + normalization (shared by both layers) ---
    init_kernel<<<nodeBlocks, 256, 0, stream>>>(deg, count, n);
    deg_count_kernel<<<edgeBlocks, 256, 0, stream>>>(col, ew, deg, count, E);
    dinv_kernel<<<nodeBlocks, 256, 0, stream>>>(deg, n);
    scan_partial_kernel<<<nodeBlocks, 256, 0, stream>>>(count, blockSum, n);
    scan_offsets_kernel<<<1, 256, 0, stream>>>(blockSum, blockOff, nodeBlocks);
    scan_final_kernel<<<nodeBlocks, 256, 0, stream>>>(count, blockOff, startA, cursor, n);
    scatter_kernel<<<edgeBlocks, 256, 0, stream>>>(row, col, ew, deg, cursor, srow, snorm, E);

    // --- layer 1 ---
    gemm128_kernel<<<512, 256, 0, stream>>>(x, W1, bufA, n);
    agg_kernel<<<n, 128, 0, stream>>>(startA, srow, snorm, deg, bufA, b1, bufB, n);

    // --- layer 2 ---
    gemm128_kernel<<<512, 256, 0, stream>>>(bufB, W2, bufA, n);
    agg_kernel<<<n, 128, 0, stream>>>(startA, srow, snorm, deg, bufA, b2, bufB, n);

    // --- readout ---
    colsum_partial_kernel<<<512, 128, 0, stream>>>(bufB, partial, n);
    final_kernel<<<1, 128, 0, stream>>>(partial, Wm, bm, out, n);
}

// Round 4
// 313.110 us; speedup vs baseline: 3.2967x; 1.9540x over previous
//
#include <hip/hip_runtime.h>

#define DD 128

typedef __attribute__((ext_vector_type(8))) short short8v;   // 8 bf16 = 4 VGPR
typedef __attribute__((ext_vector_type(4))) float float4v;   // MFMA acc

__device__ inline unsigned short f2b(float f) {              // fp32 -> bf16 RNE
    unsigned int x = __float_as_uint(f);
    return (unsigned short)((x + 0x7fffu + ((x >> 16) & 1u)) >> 16);
}
__device__ inline float blo(unsigned int u) { return __uint_as_float(u << 16); }
__device__ inline float bhi(unsigned int u) { return __uint_as_float(u & 0xffff0000u); }

// ---------------- conversions ----------------
__global__ void xconv_kernel(const float* __restrict__ x, unsigned short* __restrict__ xb,
                             int total4) {  // total4 = n*128/4
    for (int i = blockIdx.x * 256 + threadIdx.x; i < total4; i += gridDim.x * 256) {
        float4 v = ((const float4*)x)[i];
        unsigned int p0 = (unsigned int)f2b(v.x) | ((unsigned int)f2b(v.y) << 16);
        unsigned int p1 = (unsigned int)f2b(v.z) | ((unsigned int)f2b(v.w) << 16);
        ((uint2*)xb)[i] = make_uint2(p0, p1);
    }
}

// W[k][n] f32 -> Wt_hi[n][k], Wt_lo[n][k] bf16 (transposed, split precision)
__global__ void wconv_kernel(const float* __restrict__ W, unsigned short* __restrict__ WtHi,
                             unsigned short* __restrict__ WtLo) {
    int idx = blockIdx.x * 256 + threadIdx.x;  // 0..16383 = k*128+n
    int k = idx >> 7, nn = idx & 127;
    float w = W[idx];
    unsigned short hi = f2b(w);
    float rem = w - __uint_as_float(((unsigned int)hi) << 16);
    WtHi[nn * 128 + k] = hi;
    WtLo[nn * 128 + k] = f2b(rem);
}

// ---------------- degree + count ----------------
__global__ void init_kernel(float* deg, int* count, int n) {
    int i = blockIdx.x * 256 + threadIdx.x;
    if (i < n) { deg[i] = 1.0f; count[i] = 0; }
}

__global__ void deg_count_kernel(const int* __restrict__ col, const float* __restrict__ ew,
                                 float* deg, int* count, int E) {
    int e = blockIdx.x * 256 + threadIdx.x;
    if (e < E) {
        int c = col[e];
        atomicAdd(&deg[c], ew[e]);
        atomicAdd(&count[c], 1);
    }
}

__global__ void dinv_kernel(float* deg, int n) {
    int i = blockIdx.x * 256 + threadIdx.x;
    if (i < n) {
        float d = deg[i];
        deg[i] = d > 0.f ? 1.0f / sqrtf(d) : 0.f;
    }
}

// ---------------- 3-stage parallel scan ----------------
__global__ void scan_partial_kernel(const int* __restrict__ count, int* __restrict__ blockSum,
                                    int n) {
    __shared__ int s[256];
    int i = blockIdx.x * 256 + threadIdx.x;
    s[threadIdx.x] = i < n ? count[i] : 0;
    __syncthreads();
    for (int off = 128; off > 0; off >>= 1) {
        if (threadIdx.x < off) s[threadIdx.x] += s[threadIdx.x + off];
        __syncthreads();
    }
    if (threadIdx.x == 0) blockSum[blockIdx.x] = s[0];
}

__global__ void scan_offsets_kernel(const int* __restrict__ blockSum, int* __restrict__ blockOff,
                                    int nb) {
    __shared__ int s[256];
    int t = threadIdx.x;
    int v = t < nb ? blockSum[t] : 0;
    s[t] = v;
    __syncthreads();
    for (int off = 1; off < 256; off <<= 1) {
        int add = t >= off ? s[t - off] : 0;
        __syncthreads();
        s[t] += add;
        __syncthreads();
    }
    if (t < nb) blockOff[t] = s[t] - v;
}

__global__ void scan_final_kernel(const int* __restrict__ count, const int* __restrict__ blockOff,
                                  int* __restrict__ start, int* __restrict__ cursor, int n) {
    __shared__ int s[256];
    int t = threadIdx.x;
    int i = blockIdx.x * 256 + t;
    int v = i < n ? count[i] : 0;
    s[t] = v;
    __syncthreads();
    for (int off = 1; off < 256; off <<= 1) {
        int add = t >= off ? s[t - off] : 0;
        __syncthreads();
        s[t] += add;
        __syncthreads();
    }
    int excl = s[t] - v + blockOff[blockIdx.x];
    if (i < n) {
        start[i] = excl;
        cursor[i] = excl;
        if (i == n - 1) start[n] = excl + v;
    }
}

__global__ void scatter_kernel(const int* __restrict__ row, const int* __restrict__ col,
                               const float* __restrict__ ew, const float* __restrict__ dinv,
                               int* cursor, int* __restrict__ srow, float* __restrict__ snorm,
                               int E) {
    int e = blockIdx.x * 256 + threadIdx.x;
    if (e < E) {
        int c = col[e], r = row[e];
        int pos = atomicAdd(&cursor[c], 1);
        srow[pos] = r;
        snorm[pos] = dinv[r] * ew[e] * dinv[c];
    }
}

// ---------------- MFMA GEMM: C_bf16[n x 128] = A_bf16[n x 128] @ (WtHi+WtLo)^T ----------------
// Block: 256 thr = 4 waves, 128 rows. W^T staged in LDS tiled [k8][n][8] (conflict-free b128).
__global__ __launch_bounds__(256) void mfma_gemm_kernel(const unsigned short* __restrict__ A,
                                                        const unsigned short* __restrict__ WtHi,
                                                        const unsigned short* __restrict__ WtLo,
                                                        unsigned short* __restrict__ C, int n) {
    __shared__ __align__(16) unsigned short WLh[16 * 128 * 8];  // 32 KB
    __shared__ __align__(16) unsigned short WLl[16 * 128 * 8];  // 32 KB
    const int tid = threadIdx.x;

    // stage: chunk c -> (n = c>>4, k8 = c&15); global 16B at Wt[n][k8*8], LDS at (k8*128+n)*8
    for (int c = tid; c < 2048; c += 256) {
        int nn = c >> 4, k8 = c & 15;
        short8v vh = *(const short8v*)(WtHi + nn * 128 + k8 * 8);
        short8v vl = *(const short8v*)(WtLo + nn * 128 + k8 * 8);
        *(short8v*)(WLh + (k8 * 128 + nn) * 8) = vh;
        *(short8v*)(WLl + (k8 * 128 + nn) * 8) = vl;
    }
    __syncthreads();

    const int lane = tid & 63;
    const int l15 = lane & 15, l4 = lane >> 4;
    const int m0 = blockIdx.x * 128 + (tid >> 6) * 32;

    float4v acc[2][8];
#pragma unroll
    for (int i = 0; i < 2; ++i)
#pragma unroll
        for (int j = 0; j < 8; ++j) acc[i][j] = (float4v){0.f, 0.f, 0.f, 0.f};

#pragma unroll
    for (int kb = 0; kb < 4; ++kb) {
        short8v aF[2];
#pragma unroll
        for (int i = 0; i < 2; ++i) {
            int row = m0 + i * 16 + l15;
            row = row < n ? row : n - 1;  // clamp; clamped rows never stored
            aF[i] = *(const short8v*)(A + (size_t)row * 128 + kb * 32 + l4 * 8);
        }
        const int k8 = kb * 4 + l4;
#pragma unroll
        for (int j = 0; j < 8; ++j) {
            short8v bh = *(const short8v*)(WLh + (k8 * 128 + j * 16 + l15) * 8);
            short8v bl = *(const short8v*)(WLl + (k8 * 128 + j * 16 + l15) * 8);
            acc[0][j] = __builtin_amdgcn_mfma_f32_16x16x32_bf16(aF[0], bh, acc[0][j], 0, 0, 0);
            acc[1][j] = __builtin_amdgcn_mfma_f32_16x16x32_bf16(aF[1], bh, acc[1][j], 0, 0, 0);
            acc[0][j] = __builtin_amdgcn_mfma_f32_16x16x32_bf16(aF[0], bl, acc[0][j], 0, 0, 0);
            acc[1][j] = __builtin_amdgcn_mfma_f32_16x16x32_bf16(aF[1], bl, acc[1][j], 0, 0, 0);
        }
    }

    // C/D layout (m89-verified): col = lane&15, row = (lane>>4)*4 + reg
#pragma unroll
    for (int i = 0; i < 2; ++i)
#pragma unroll
        for (int r = 0; r < 4; ++r) {
            int row = m0 + i * 16 + l4 * 4 + r;
            if (row < n) {
#pragma unroll
                for (int j = 0; j < 8; ++j)
                    C[(size_t)row * 128 + j * 16 + l15] = f2b(acc[i][j][r]);
            }
        }
}

// ---------------- pull aggregation: 1 wave per node, bf16 gather, no atomics ----------------
__global__ __launch_bounds__(64) void agg_kernel(const int* __restrict__ start,
                                                 const int* __restrict__ srow,
                                                 const float* __restrict__ snorm,
                                                 const float* __restrict__ dinv,
                                                 const unsigned short* __restrict__ xw,
                                                 const float* __restrict__ bias,
                                                 unsigned short* __restrict__ h, int n) {
    const int i = blockIdx.x;
    const int t = threadIdx.x;  // features 2t, 2t+1
    const float dv = dinv[i];
    unsigned int u = *(const unsigned int*)(xw + (size_t)i * DD + 2 * t);
    float a0 = dv * dv * blo(u);
    float a1 = dv * dv * bhi(u);
    const int s = start[i], e = start[i + 1];
    int k = s;
    for (; k + 3 < e; k += 4) {
        int r0 = srow[k], r1 = srow[k + 1], r2 = srow[k + 2], r3 = srow[k + 3];
        float n0 = snorm[k], n1 = snorm[k + 1], n2 = snorm[k + 2], n3 = snorm[k + 3];
        unsigned int u0 = *(const unsigned int*)(xw + (size_t)r0 * DD + 2 * t);
        unsigned int u1 = *(const unsigned int*)(xw + (size_t)r1 * DD + 2 * t);
        unsigned int u2 = *(const unsigned int*)(xw + (size_t)r2 * DD + 2 * t);
        unsigned int u3 = *(const unsigned int*)(xw + (size_t)r3 * DD + 2 * t);
        a0 += n0 * blo(u0); a1 += n0 * bhi(u0);
        a0 += n1 * blo(u1); a1 += n1 * bhi(u1);
        a0 += n2 * blo(u2); a1 += n2 * bhi(u2);
        a0 += n3 * blo(u3); a1 += n3 * bhi(u3);
    }
    for (; k < e; ++k) {
        int r = srow[k];
        float nv = snorm[k];
        unsigned int uu = *(const unsigned int*)(xw + (size_t)r * DD + 2 * t);
        a0 += nv * blo(uu); a1 += nv * bhi(uu);
    }
    a0 = fmaxf(a0 + bias[2 * t], 0.f);
    a1 = fmaxf(a1 + bias[2 * t + 1], 0.f);
    *(unsigned int*)(h + (size_t)i * DD + 2 * t) =
        (unsigned int)f2b(a0) | ((unsigned int)f2b(a1) << 16);
}

// ---------------- readout ----------------
__global__ __launch_bounds__(64) void colsum_partial_kernel(const unsigned short* __restrict__ h,
                                                            float* __restrict__ partial, int n) {
    int t = threadIdx.x;
    float a0 = 0.f, a1 = 0.f;
    for (int r = blockIdx.x; r < n; r += gridDim.x) {
        unsigned int u = *(const unsigned int*)(h + (size_t)r * DD + 2 * t);
        a0 += blo(u); a1 += bhi(u);
    }
    partial[blockIdx.x * DD + 2 * t] = a0;
    partial[blockIdx.x * DD + 2 * t + 1] = a1;
}

__global__ void final_kernel(const float* __restrict__ partial, const float* __restrict__ Wm,
                             const float* __restrict__ bm, float* __restrict__ out, int n) {
    __shared__ float g[DD];
    int t = threadIdx.x;
    float acc = 0.f;
    for (int b = 0; b < 512; ++b) acc += partial[b * DD + t];
    g[t] = acc / (float)n;
    __syncthreads();
    if (t < 10) {
        float o = bm[t];
#pragma unroll
        for (int d = 0; d < DD; ++d) o += g[d] * Wm[d * 10 + t];
        out[t] = o;
    }
}

extern "C" void kernel_launch(void* const* d_in, const int* in_sizes, int n_in,
                              void* d_out, int out_size, void* d_ws, size_t ws_size,
                              hipStream_t stream) {
    const float* x  = (const float*)d_in[0];
    const int*   ei = (const int*)d_in[1];
    const float* ew = (const float*)d_in[2];
    const float* W1 = (const float*)d_in[3];
    const float* b1 = (const float*)d_in[4];
    const float* W2 = (const float*)d_in[5];
    const float* b2 = (const float*)d_in[6];
    const float* Wm = (const float*)d_in[7];
    const float* bm = (const float*)d_in[8];
    float* out = (float*)d_out;

    const int n = in_sizes[0] / DD;   // 50000
    const int E = in_sizes[2];        // 800000
    const int* row = ei;
    const int* col = ei + E;

    const int nodeBlocks = (n + 255) / 256;   // 196
    const int edgeBlocks = (E + 255) / 256;

    float* ws = (float*)d_ws;
    float* deg     = ws;                          // n
    float* snorm   = deg + n;                     // E
    float* partial = snorm + E;                   // 512*128
    int*   count   = (int*)(partial + 512 * DD);  // n
    int*   startA  = count + n;                   // n+1
    int*   cursor  = startA + (n + 1);            // n
    int*   srow    = cursor + n;                  // E
    int*   blockSum = srow + E;                   // nodeBlocks
    int*   blockOff = blockSum + nodeBlocks;      // nodeBlocks
    // 16B-align the bf16 region
    uintptr_t p = (uintptr_t)(blockOff + nodeBlocks);
    p = (p + 15) & ~(uintptr_t)15;
    unsigned short* xb   = (unsigned short*)p;    // n*128 bf16
    unsigned short* T0   = xb + (size_t)n * DD;   // n*128 bf16 (xw)
    unsigned short* T1   = T0 + (size_t)n * DD;   // n*128 bf16 (h)
    unsigned short* Wt1h = T1 + (size_t)n * DD;   // 16384 each
    unsigned short* Wt1l = Wt1h + 16384;
    unsigned short* Wt2h = Wt1l + 16384;
    unsigned short* Wt2l = Wt2h + 16384;

    // --- conversions ---
    xconv_kernel<<<1024, 256, 0, stream>>>(x, xb, n * DD / 4);
    wconv_kernel<<<64, 256, 0, stream>>>(W1, Wt1h, Wt1l);
    wconv_kernel<<<64, 256, 0, stream>>>(W2, Wt2h, Wt2l);

    // --- CSR + normalization ---
    init_kernel<<<nodeBlocks, 256, 0, stream>>>(deg, count, n);
    deg_count_kernel<<<edgeBlocks, 256, 0, stream>>>(col, ew, deg, count, E);
    dinv_kernel<<<nodeBlocks, 256, 0, stream>>>(deg, n);
    scan_partial_kernel<<<nodeBlocks, 256, 0, stream>>>(count, blockSum, n);
    scan_offsets_kernel<<<1, 256, 0, stream>>>(blockSum, blockOff, nodeBlocks);
    scan_final_kernel<<<nodeBlocks, 256, 0, stream>>>(count, blockOff, startA, cursor, n);
    scatter_kernel<<<edgeBlocks, 256, 0, stream>>>(row, col, ew, deg, cursor, srow, snorm, E);

    const int gemmBlocks = (n + 127) / 128;  // 391

    // --- layer 1 ---
    mfma_gemm_kernel<<<gemmBlocks, 256, 0, stream>>>(xb, Wt1h, Wt1l, T0, n);
    agg_kernel<<<n, 64, 0, stream>>>(startA, srow, snorm, deg, T0, b1, T1, n);

    // --- layer 2 ---
    mfma_gemm_kernel<<<gemmBlocks, 256, 0, stream>>>(T1, Wt2h, Wt2l, T0, n);
    agg_kernel<<<n, 64, 0, stream>>>(startA, srow, snorm, deg, T0, b2, T1, n);

    // --- readout ---
    colsum_partial_kernel<<<512, 64, 0, stream>>>(T1, partial, n);
    final_kernel<<<1, 128, 0, stream>>>(partial, Wm, bm, out, n);
}